// Round 4
// baseline (610.183 us; speedup 1.0000x reference)
//
#include <hip/hip_runtime.h>
#include <math.h>

#define NUM_USERS 100000
#define NUM_ITEMS 200000
#define N_NODES   300000   // NUM_USERS + NUM_ITEMS
#define EMB       64
#define NUM_INTER 1000000
#define N_EDGES   (2 * NUM_INTER)
#define MAX_SLOTS (N_EDGES + 7 * N_NODES + 16)   // rows padded to multiple of 8
#define BATCH     16384
#define SCAN_BLOCK 1024

// ---------- small kernels ----------

__global__ void softmax4_k(const float* __restrict__ lw, float* __restrict__ w) {
    if (threadIdx.x == 0 && blockIdx.x == 0) {
        float a = lw[0], b = lw[1], c = lw[2], d = lw[3];
        float m = fmaxf(fmaxf(a, b), fmaxf(c, d));
        float e0 = expf(a - m), e1 = expf(b - m), e2 = expf(c - m), e3 = expf(d - m);
        float s = e0 + e1 + e2 + e3;
        w[0] = e0 / s; w[1] = e1 / s; w[2] = e2 / s; w[3] = e3 / s;
    }
}

__global__ void degree_k(const int* __restrict__ iu, const int* __restrict__ ii,
                         int* __restrict__ deg) {
    int e = blockIdx.x * blockDim.x + threadIdx.x;
    if (e < NUM_INTER) {
        atomicAdd(&deg[iu[e]], 1);
        atomicAdd(&deg[NUM_USERS + ii[e]], 1);
    }
}

// dinv = deg^-1/2, d2 = deg^-1, rcp = deg^1/2 (0 where deg==0), pdeg = deg padded to x8
__global__ void dinv_k(const int* __restrict__ deg, float* __restrict__ dinv,
                       float* __restrict__ d2, float* __restrict__ rcp,
                       int* __restrict__ pdeg) {
    int n = blockIdx.x * blockDim.x + threadIdx.x;
    if (n < N_NODES) {
        int d = deg[n];
        float fd = (float)d;
        dinv[n] = (d > 0) ? (1.0f / sqrtf(fd)) : 0.0f;
        d2[n]   = (d > 0) ? (1.0f / fd) : 0.0f;
        rcp[n]  = (d > 0) ? sqrtf(fd) : 0.0f;
        pdeg[n] = (d + 7) & ~7;
    }
}

// ---------- exclusive scan of pdeg -> row_start ----------

__global__ void block_sum_k(const int* __restrict__ v, int* __restrict__ bsum, int n) {
    __shared__ int lds[SCAN_BLOCK];
    int g = blockIdx.x * SCAN_BLOCK + threadIdx.x;
    lds[threadIdx.x] = (g < n) ? v[g] : 0;
    __syncthreads();
    for (int s = SCAN_BLOCK / 2; s > 0; s >>= 1) {
        if (threadIdx.x < s) lds[threadIdx.x] += lds[threadIdx.x + s];
        __syncthreads();
    }
    if (threadIdx.x == 0) bsum[blockIdx.x] = lds[0];
}

// single block; nb <= 512, exclusive scan in-place
__global__ void scan_bsum_k(int* __restrict__ bsum, int nb) {
    __shared__ int lds[512];
    int t = threadIdx.x;
    int v = (t < nb) ? bsum[t] : 0;
    lds[t] = v;
    __syncthreads();
    for (int ofs = 1; ofs < 512; ofs <<= 1) {
        int x = (t >= ofs) ? lds[t - ofs] : 0;
        __syncthreads();
        lds[t] += x;
        __syncthreads();
    }
    if (t < nb) bsum[t] = lds[t] - v;   // exclusive
}

__global__ void scan_block_k(const int* __restrict__ v, const int* __restrict__ bsum,
                             int* __restrict__ row_start, int n) {
    __shared__ int lds[SCAN_BLOCK];
    int g = blockIdx.x * SCAN_BLOCK + threadIdx.x;
    int x = (g < n) ? v[g] : 0;
    lds[threadIdx.x] = x;
    __syncthreads();
    for (int ofs = 1; ofs < SCAN_BLOCK; ofs <<= 1) {
        int y = (threadIdx.x >= ofs) ? lds[threadIdx.x - ofs] : 0;
        __syncthreads();
        lds[threadIdx.x] += y;
        __syncthreads();
    }
    if (g < n) row_start[g] = bsum[blockIdx.x] + lds[threadIdx.x] - x;  // exclusive
    if (g == n - 1) row_start[n] = bsum[blockIdx.x] + lds[threadIdx.x]; // inclusive total
}

// ---------- CSR fill (neighbor index only) ----------

__global__ void fill_csr_k(const int* __restrict__ iu, const int* __restrict__ ii,
                           const int* __restrict__ row_start,
                           int* __restrict__ fill, int* __restrict__ nbr) {
    int e = blockIdx.x * blockDim.x + threadIdx.x;
    if (e < NUM_INTER) {
        int u  = iu[e];
        int it = NUM_USERS + ii[e];
        int p0 = row_start[u]  + atomicAdd(&fill[u],  1);
        nbr[p0] = it;
        int p1 = row_start[it] + atomicAdd(&fill[it], 1);
        nbr[p1] = u;
    }
}

// fill pad slots [row_start[n]+deg[n], row_start[n+1]) with the dummy zero node
__global__ void pad_fill_k(const int* __restrict__ deg, const int* __restrict__ row_start,
                           int* __restrict__ nbr) {
    int n = blockIdx.x * blockDim.x + threadIdx.x;
    if (n < N_NODES) {
        int e0 = row_start[n] + deg[n];
        int e1 = row_start[n + 1];
        for (int j = e0; j < e1; ++j) nbr[j] = N_NODES;
    }
}

// zero the dummy rows (node N_NODES) of both z buffers
__global__ void zero_dummy_k(float* __restrict__ z0, float* __restrict__ z1) {
    int t = threadIdx.x;   // 64 threads
    z0[(size_t)N_NODES * EMB + t] = 0.0f;
    z1[(size_t)N_NODES * EMB + t] = 0.0f;
}

// z0 = dinv ⊙ concat(user_emb, item_emb)   (16 threads/node, float4 lanes)
__global__ void scale_k(const float* __restrict__ ue, const float* __restrict__ ie,
                        const float* __restrict__ dinv, float* __restrict__ z) {
    int t = blockIdx.x * blockDim.x + threadIdx.x;
    int node = t >> 4;
    int q = t & 15;
    if (node >= N_NODES) return;
    const float4* src = (node < NUM_USERS)
        ? (const float4*)ue + (size_t)node * 16
        : (const float4*)ie + (size_t)(node - NUM_USERS) * 16;
    float s = dinv[node];
    float4 v = src[q];
    ((float4*)z)[(size_t)node * 16 + q] = make_float4(s * v.x, s * v.y, s * v.z, s * v.w);
}

// ---------- propagation: z_next[v] = d2[v] * sum_{n in N(v)} z[n] ----------

__global__ void prop_k(const int* __restrict__ row_start, const int* __restrict__ nbr,
                       const float* __restrict__ d2,
                       const float* __restrict__ in, float* __restrict__ out) {
    int t = blockIdx.x * blockDim.x + threadIdx.x;
    int node = t >> 4;
    int q = t & 15;
    if (node >= N_NODES) return;
    int beg = row_start[node], end = row_start[node + 1];
    const float4* in4 = (const float4*)in;
    float4 acc = make_float4(0.f, 0.f, 0.f, 0.f);
    for (int j = beg; j < end; j += 8) {
        int4 na = *(const int4*)(nbr + j);
        int4 nb = *(const int4*)(nbr + j + 4);
        float4 g0 = in4[(size_t)na.x * 16 + q];
        float4 g1 = in4[(size_t)na.y * 16 + q];
        float4 g2 = in4[(size_t)na.z * 16 + q];
        float4 g3 = in4[(size_t)na.w * 16 + q];
        float4 g4 = in4[(size_t)nb.x * 16 + q];
        float4 g5 = in4[(size_t)nb.y * 16 + q];
        float4 g6 = in4[(size_t)nb.z * 16 + q];
        float4 g7 = in4[(size_t)nb.w * 16 + q];
        acc.x += g0.x + g1.x + g2.x + g3.x + g4.x + g5.x + g6.x + g7.x;
        acc.y += g0.y + g1.y + g2.y + g3.y + g4.y + g5.y + g6.y + g7.y;
        acc.z += g0.z + g1.z + g2.z + g3.z + g4.z + g5.z + g6.z + g7.z;
        acc.w += g0.w + g1.w + g2.w + g3.w + g4.w + g5.w + g6.w + g7.w;
    }
    float s = d2[node];
    ((float4*)out)[(size_t)node * 16 + q] =
        make_float4(s * acc.x, s * acc.y, s * acc.z, s * acc.w);
}

// ---------- epilogue ----------

__global__ void gather0_k(const float* __restrict__ ue, const float* __restrict__ ie,
                          const int* __restrict__ uid, const int* __restrict__ iid,
                          const float* __restrict__ w,
                          float* __restrict__ fu, float* __restrict__ fi) {
    int idx = blockIdx.x * blockDim.x + threadIdx.x;
    if (idx < BATCH * EMB) {
        int b = idx >> 6, d = idx & 63;
        float w0 = w[0];
        fu[idx] = w0 * ue[(size_t)uid[b] * EMB + d];
        fi[idx] = w0 * ie[(size_t)iid[b] * EMB + d];
    }
}

// fu += w[wi] * rcp[node] * z[node]   (recovers true embedding from scaled z)
__global__ void gather_acc_k(const float* __restrict__ z, const float* __restrict__ rcp,
                             const int* __restrict__ uid, const int* __restrict__ iid,
                             const float* __restrict__ w, int wi,
                             float* __restrict__ fu, float* __restrict__ fi) {
    int idx = blockIdx.x * blockDim.x + threadIdx.x;
    if (idx < BATCH * EMB) {
        int b = idx >> 6, d = idx & 63;
        float wl = w[wi];
        int un = uid[b];
        int in_ = NUM_USERS + iid[b];
        fu[idx] += wl * rcp[un]  * z[(size_t)un  * EMB + d];
        fi[idx] += wl * rcp[in_] * z[(size_t)in_ * EMB + d];
    }
}

__global__ void score_k(const float* __restrict__ fu, const float* __restrict__ fi,
                        float* __restrict__ out) {
    int idx = blockIdx.x * blockDim.x + threadIdx.x;
    int b = idx >> 6, d = idx & 63;
    float v = fu[idx] * fi[idx];
    #pragma unroll
    for (int off = 32; off > 0; off >>= 1)
        v += __shfl_down(v, off, 64);
    if (d == 0) out[b] = v;
}

// ---------- launch ----------

extern "C" void kernel_launch(void* const* d_in, const int* in_sizes, int n_in,
                              void* d_out, int out_size, void* d_ws, size_t ws_size,
                              hipStream_t stream) {
    const float* user_emb = (const float*)d_in[0];
    const float* item_emb = (const float*)d_in[1];
    const float* layer_w  = (const float*)d_in[2];
    const int*   inter_u  = (const int*)d_in[3];
    const int*   inter_i  = (const int*)d_in[4];
    const int*   user_ids = (const int*)d_in[5];
    const int*   item_ids = (const int*)d_in[6];
    float* out = (float*)d_out;

    char* base = (char*)d_ws;
    size_t off = 0;
    auto alloc = [&](size_t bytes) -> char* {
        char* p = base + off;
        off = (off + bytes + 255) & ~(size_t)255;
        return p;
    };
    float* w4        = (float*)alloc(4 * sizeof(float));
    int*   deg       = (int*)  alloc((size_t)N_NODES * sizeof(int));
    int*   pdeg      = (int*)  alloc((size_t)N_NODES * sizeof(int));
    float* dinv      = (float*)alloc((size_t)N_NODES * sizeof(float));
    float* d2        = (float*)alloc((size_t)N_NODES * sizeof(float));
    float* rcp       = (float*)alloc((size_t)N_NODES * sizeof(float));
    int*   row_start = (int*)  alloc(((size_t)N_NODES + 1) * sizeof(int));
    int*   bsum      = (int*)  alloc(512 * sizeof(int));
    int*   fill      = (int*)  alloc((size_t)N_NODES * sizeof(int));
    int*   csr_nbr   = (int*)  alloc((size_t)MAX_SLOTS * sizeof(int));
    float* z0        = (float*)alloc(((size_t)N_NODES + 1) * EMB * sizeof(float));
    float* z1        = (float*)alloc(((size_t)N_NODES + 1) * EMB * sizeof(float));
    float* fu        = (float*)alloc((size_t)BATCH * EMB * sizeof(float));
    float* fi        = (float*)alloc((size_t)BATCH * EMB * sizeof(float));

    const int nscan_blocks = (N_NODES + SCAN_BLOCK - 1) / SCAN_BLOCK;   // 293

    // 1. softmax weights
    softmax4_k<<<1, 64, 0, stream>>>(layer_w, w4);

    // 2. degrees + per-node factors
    hipMemsetAsync(deg, 0, (size_t)N_NODES * sizeof(int), stream);
    degree_k<<<(NUM_INTER + 255) / 256, 256, 0, stream>>>(inter_u, inter_i, deg);
    dinv_k<<<(N_NODES + 255) / 256, 256, 0, stream>>>(deg, dinv, d2, rcp, pdeg);

    // 3. exclusive scan pdeg -> row_start (padded CSR)
    block_sum_k<<<nscan_blocks, SCAN_BLOCK, 0, stream>>>(pdeg, bsum, N_NODES);
    scan_bsum_k<<<1, 512, 0, stream>>>(bsum, nscan_blocks);
    scan_block_k<<<nscan_blocks, SCAN_BLOCK, 0, stream>>>(pdeg, bsum, row_start, N_NODES);

    // 4. CSR fill (nbr only) + pad slots -> dummy node
    hipMemsetAsync(fill, 0, (size_t)N_NODES * sizeof(int), stream);
    fill_csr_k<<<(NUM_INTER + 255) / 256, 256, 0, stream>>>(
        inter_u, inter_i, row_start, fill, csr_nbr);
    pad_fill_k<<<(N_NODES + 255) / 256, 256, 0, stream>>>(deg, row_start, csr_nbr);
    zero_dummy_k<<<1, 64, 0, stream>>>(z0, z1);

    // 5. z0 = dinv ⊙ concat(user_emb, item_emb)
    const int per_node_threads = N_NODES * 16;
    const int per_node_blocks = (per_node_threads + 255) / 256;
    scale_k<<<per_node_blocks, 256, 0, stream>>>(user_emb, item_emb, dinv, z0);

    // 6. layer-0 contribution at queried nodes
    gather0_k<<<(BATCH * EMB + 255) / 256, 256, 0, stream>>>(
        user_emb, item_emb, user_ids, item_ids, w4, fu, fi);

    // 7. 3 propagation layers in scaled space
    prop_k<<<per_node_blocks, 256, 0, stream>>>(row_start, csr_nbr, d2, z0, z1);
    gather_acc_k<<<(BATCH * EMB + 255) / 256, 256, 0, stream>>>(
        z1, rcp, user_ids, item_ids, w4, 1, fu, fi);

    prop_k<<<per_node_blocks, 256, 0, stream>>>(row_start, csr_nbr, d2, z1, z0);
    gather_acc_k<<<(BATCH * EMB + 255) / 256, 256, 0, stream>>>(
        z0, rcp, user_ids, item_ids, w4, 2, fu, fi);

    prop_k<<<per_node_blocks, 256, 0, stream>>>(row_start, csr_nbr, d2, z0, z1);
    gather_acc_k<<<(BATCH * EMB + 255) / 256, 256, 0, stream>>>(
        z1, rcp, user_ids, item_ids, w4, 3, fu, fi);

    // 8. scores
    score_k<<<(BATCH * EMB + 255) / 256, 256, 0, stream>>>(fu, fi, out);
}

// Round 6
// 513.666 us; speedup vs baseline: 1.1879x; 1.1879x over previous
//
#include <hip/hip_runtime.h>
#include <math.h>

#define NUM_USERS 100000
#define NUM_ITEMS 200000
#define N_NODES   300000   // NUM_USERS + NUM_ITEMS
#define EMB       64
#define NUM_INTER 1000000
#define N_EDGES   (2 * NUM_INTER)
#define MAX_SLOTS (N_EDGES + 3 * N_NODES + 16)   // rows padded to multiple of 4
#define BATCH     16384
#define SCAN_BLOCK 1024

typedef float vfloat4 __attribute__((ext_vector_type(4)));

// ---------- small kernels ----------

__global__ void softmax4_k(const float* __restrict__ lw, float* __restrict__ w) {
    if (threadIdx.x == 0 && blockIdx.x == 0) {
        float a = lw[0], b = lw[1], c = lw[2], d = lw[3];
        float m = fmaxf(fmaxf(a, b), fmaxf(c, d));
        float e0 = expf(a - m), e1 = expf(b - m), e2 = expf(c - m), e3 = expf(d - m);
        float s = e0 + e1 + e2 + e3;
        w[0] = e0 / s; w[1] = e1 / s; w[2] = e2 / s; w[3] = e3 / s;
    }
}

__global__ void degree_k(const int* __restrict__ iu, const int* __restrict__ ii,
                         int* __restrict__ deg) {
    int e = blockIdx.x * blockDim.x + threadIdx.x;
    if (e < NUM_INTER) {
        atomicAdd(&deg[iu[e]], 1);
        atomicAdd(&deg[NUM_USERS + ii[e]], 1);
    }
}

// dinv = deg^-1/2, rcp = deg^1/2, d2 = deg^-1 (0 where deg==0), pdeg = deg padded to x4
__global__ void dinv_k(const int* __restrict__ deg, float* __restrict__ dinv,
                       float* __restrict__ d2, float* __restrict__ rcp,
                       int* __restrict__ pdeg) {
    int n = blockIdx.x * blockDim.x + threadIdx.x;
    if (n < N_NODES) {
        int d = deg[n];
        float fd = (float)d;
        dinv[n] = (d > 0) ? (1.0f / sqrtf(fd)) : 0.0f;
        d2[n]   = (d > 0) ? (1.0f / fd) : 0.0f;
        rcp[n]  = (d > 0) ? sqrtf(fd) : 0.0f;
        pdeg[n] = (d + 3) & ~3;
    }
}

// ---------- exclusive scan of pdeg -> row_start ----------

__global__ void block_sum_k(const int* __restrict__ v, int* __restrict__ bsum, int n) {
    __shared__ int lds[SCAN_BLOCK];
    int g = blockIdx.x * SCAN_BLOCK + threadIdx.x;
    lds[threadIdx.x] = (g < n) ? v[g] : 0;
    __syncthreads();
    for (int s = SCAN_BLOCK / 2; s > 0; s >>= 1) {
        if (threadIdx.x < s) lds[threadIdx.x] += lds[threadIdx.x + s];
        __syncthreads();
    }
    if (threadIdx.x == 0) bsum[blockIdx.x] = lds[0];
}

// single block; nb <= 512, exclusive scan in-place
__global__ void scan_bsum_k(int* __restrict__ bsum, int nb) {
    __shared__ int lds[512];
    int t = threadIdx.x;
    int v = (t < nb) ? bsum[t] : 0;
    lds[t] = v;
    __syncthreads();
    for (int ofs = 1; ofs < 512; ofs <<= 1) {
        int x = (t >= ofs) ? lds[t - ofs] : 0;
        __syncthreads();
        lds[t] += x;
        __syncthreads();
    }
    if (t < nb) bsum[t] = lds[t] - v;   // exclusive
}

__global__ void scan_block_k(const int* __restrict__ v, const int* __restrict__ bsum,
                             int* __restrict__ row_start, int n) {
    __shared__ int lds[SCAN_BLOCK];
    int g = blockIdx.x * SCAN_BLOCK + threadIdx.x;
    int x = (g < n) ? v[g] : 0;
    lds[threadIdx.x] = x;
    __syncthreads();
    for (int ofs = 1; ofs < SCAN_BLOCK; ofs <<= 1) {
        int y = (threadIdx.x >= ofs) ? lds[threadIdx.x - ofs] : 0;
        __syncthreads();
        lds[threadIdx.x] += y;
        __syncthreads();
    }
    if (g < n) row_start[g] = bsum[blockIdx.x] + lds[threadIdx.x] - x;  // exclusive
    if (g == n - 1) row_start[n] = bsum[blockIdx.x] + lds[threadIdx.x]; // inclusive total
}

// ---------- CSR fill: 4 interactions per thread (int4 index reads) ----------

__global__ void fill_csr_k(const int* __restrict__ iu, const int* __restrict__ ii,
                           const int* __restrict__ row_start,
                           int* __restrict__ fill, int* __restrict__ nbr) {
    int t = blockIdx.x * blockDim.x + threadIdx.x;   // < NUM_INTER/4
    if (t >= NUM_INTER / 4) return;
    int4 u4 = ((const int4*)iu)[t];
    int4 i4 = ((const int4*)ii)[t];
    #pragma unroll
    for (int k = 0; k < 4; ++k) {
        int u  = (&u4.x)[k];
        int it = NUM_USERS + (&i4.x)[k];
        int p0 = row_start[u]  + atomicAdd(&fill[u],  1);
        nbr[p0] = it;
        int p1 = row_start[it] + atomicAdd(&fill[it], 1);
        nbr[p1] = u;
    }
}

// fill pad slots [row_start[n]+deg[n], row_start[n+1]) with the dummy zero node
__global__ void pad_fill_k(const int* __restrict__ deg, const int* __restrict__ row_start,
                           int* __restrict__ nbr) {
    int n = blockIdx.x * blockDim.x + threadIdx.x;
    if (n < N_NODES) {
        int e0 = row_start[n] + deg[n];
        int e1 = row_start[n + 1];
        for (int j = e0; j < e1; ++j) nbr[j] = N_NODES;
    }
}

// zero dummy row (node N_NODES) of both z buffers
__global__ void zero_dummy_k(float* __restrict__ zA, float* __restrict__ zB) {
    int t = threadIdx.x;   // 64 threads
    zA[(size_t)N_NODES * EMB + t] = 0.0f;
    zB[(size_t)N_NODES * EMB + t] = 0.0f;
}

// z0 = dinv ⊙ concat(user_emb, item_emb)   (16 threads/node, float4 lanes)
__global__ void scale_k(const float* __restrict__ ue, const float* __restrict__ ie,
                        const float* __restrict__ dinv, float* __restrict__ z) {
    int t = blockIdx.x * blockDim.x + threadIdx.x;
    int node = t >> 4;
    int q = t & 15;
    if (node >= N_NODES) return;
    const float4* src = (node < NUM_USERS)
        ? (const float4*)ue + (size_t)node * 16
        : (const float4*)ie + (size_t)(node - NUM_USERS) * 16;
    float s = dinv[node];
    float4 v = src[q];
    vfloat4 r = { s * v.x, s * v.y, s * v.z, s * v.w };
    __builtin_nontemporal_store(r, (vfloat4*)z + (size_t)node * 16 + q);
}

// ---------- propagation: z_next[v] = d2[v] * sum_{n in N(v)} z[n] ----------

__global__ void prop_k(const int* __restrict__ row_start, const int* __restrict__ nbr,
                       const float* __restrict__ d2,
                       const float* __restrict__ in, float* __restrict__ out) {
    int t = blockIdx.x * blockDim.x + threadIdx.x;
    int node = t >> 4;
    int q = t & 15;
    if (node >= N_NODES) return;
    int beg = row_start[node], end = row_start[node + 1];
    const float4* in4 = (const float4*)in;
    float4 acc = make_float4(0.f, 0.f, 0.f, 0.f);
    for (int j = beg; j < end; j += 4) {
        int4 n = *(const int4*)(nbr + j);
        float4 g0 = in4[(size_t)n.x * 16 + q];
        float4 g1 = in4[(size_t)n.y * 16 + q];
        float4 g2 = in4[(size_t)n.z * 16 + q];
        float4 g3 = in4[(size_t)n.w * 16 + q];
        acc.x += g0.x + g1.x + g2.x + g3.x;
        acc.y += g0.y + g1.y + g2.y + g3.y;
        acc.z += g0.z + g1.z + g2.z + g3.z;
        acc.w += g0.w + g1.w + g2.w + g3.w;
    }
    float s = d2[node];
    vfloat4 r = { s * acc.x, s * acc.y, s * acc.z, s * acc.w };
    __builtin_nontemporal_store(r, (vfloat4*)out + (size_t)node * 16 + q);
}

// ---------- fused epilogue: layer-3 pull at queried nodes + layers 0-2 + dot ----------
// 32 threads per batch slot: side = user/item (16 lanes each), q = float4 chunk.
// F(v) = w0*emb[v] + rcp[v]*(w1*z1[v] + w2*z2[v]) + w3*dinv[v]*sum_{n in N(v)} z2[n]
// out[slot] = dot(F(uid), F(iid))

__global__ void fused_score_k(const int* __restrict__ row_start, const int* __restrict__ nbr,
                              const float* __restrict__ dinv, const float* __restrict__ rcp,
                              const float* __restrict__ ue, const float* __restrict__ ie,
                              const float* __restrict__ z1, const float* __restrict__ z2,
                              const int* __restrict__ uid, const int* __restrict__ iid,
                              const float* __restrict__ w4, float* __restrict__ out) {
    int t = blockIdx.x * blockDim.x + threadIdx.x;
    int slot = t >> 5;
    if (slot >= BATCH) return;
    int within = t & 31;
    int side = within >> 4;
    int q = within & 15;

    int node;
    const float4* erow;
    if (side == 0) {
        int u = uid[slot];
        node = u;
        erow = (const float4*)ue + (size_t)u * 16;
    } else {
        int ii_ = iid[slot];
        node = NUM_USERS + ii_;
        erow = (const float4*)ie + (size_t)ii_ * 16;
    }

    float w0 = w4[0], w1 = w4[1], w2 = w4[2], w3 = w4[3];
    int beg = row_start[node], end = row_start[node + 1];
    const float4* z2v = (const float4*)z2;

    float4 acc = make_float4(0.f, 0.f, 0.f, 0.f);
    for (int j = beg; j < end; j += 4) {
        int4 n = *(const int4*)(nbr + j);
        float4 g0 = z2v[(size_t)n.x * 16 + q];
        float4 g1 = z2v[(size_t)n.y * 16 + q];
        float4 g2 = z2v[(size_t)n.z * 16 + q];
        float4 g3 = z2v[(size_t)n.w * 16 + q];
        acc.x += g0.x + g1.x + g2.x + g3.x;
        acc.y += g0.y + g1.y + g2.y + g3.y;
        acc.z += g0.z + g1.z + g2.z + g3.z;
        acc.w += g0.w + g1.w + g2.w + g3.w;
    }

    float r  = rcp[node];
    float di = dinv[node];
    float4 e  = erow[q];
    float4 a1 = ((const float4*)z1)[(size_t)node * 16 + q];
    float4 a2 = z2v[(size_t)node * 16 + q];

    float4 f;
    f.x = w0 * e.x + r * (w1 * a1.x + w2 * a2.x) + w3 * di * acc.x;
    f.y = w0 * e.y + r * (w1 * a1.y + w2 * a2.y) + w3 * di * acc.y;
    f.z = w0 * e.z + r * (w1 * a1.z + w2 * a2.z) + w3 * di * acc.z;
    f.w = w0 * e.w + r * (w1 * a1.w + w2 * a2.w) + w3 * di * acc.w;

    // exchange with the other side (lane ^ 16 within the wave)
    float4 o;
    o.x = __shfl_xor(f.x, 16);
    o.y = __shfl_xor(f.y, 16);
    o.z = __shfl_xor(f.z, 16);
    o.w = __shfl_xor(f.w, 16);

    float p = f.x * o.x + f.y * o.y + f.z * o.z + f.w * o.w;
    p += __shfl_xor(p, 1);
    p += __shfl_xor(p, 2);
    p += __shfl_xor(p, 4);
    p += __shfl_xor(p, 8);

    if (within == 0) out[slot] = p;
}

// ---------- launch ----------

extern "C" void kernel_launch(void* const* d_in, const int* in_sizes, int n_in,
                              void* d_out, int out_size, void* d_ws, size_t ws_size,
                              hipStream_t stream) {
    const float* user_emb = (const float*)d_in[0];
    const float* item_emb = (const float*)d_in[1];
    const float* layer_w  = (const float*)d_in[2];
    const int*   inter_u  = (const int*)d_in[3];
    const int*   inter_i  = (const int*)d_in[4];
    const int*   user_ids = (const int*)d_in[5];
    const int*   item_ids = (const int*)d_in[6];
    float* out = (float*)d_out;

    char* base = (char*)d_ws;
    size_t off = 0;
    auto alloc = [&](size_t bytes) -> char* {
        char* p = base + off;
        off = (off + bytes + 255) & ~(size_t)255;
        return p;
    };
    float* w4        = (float*)alloc(4 * sizeof(float));
    int*   deg       = (int*)  alloc((size_t)N_NODES * sizeof(int));
    int*   pdeg      = (int*)  alloc((size_t)N_NODES * sizeof(int));
    float* dinv      = (float*)alloc((size_t)N_NODES * sizeof(float));
    float* d2        = (float*)alloc((size_t)N_NODES * sizeof(float));
    float* rcp       = (float*)alloc((size_t)N_NODES * sizeof(float));
    int*   row_start = (int*)  alloc(((size_t)N_NODES + 1) * sizeof(int));
    int*   bsum      = (int*)  alloc(512 * sizeof(int));
    int*   fill      = (int*)  alloc((size_t)N_NODES * sizeof(int));
    int*   csr_nbr   = (int*)  alloc((size_t)MAX_SLOTS * sizeof(int));
    float* zA        = (float*)alloc(((size_t)N_NODES + 1) * EMB * sizeof(float));
    float* zB        = (float*)alloc(((size_t)N_NODES + 1) * EMB * sizeof(float));

    const int nscan_blocks = (N_NODES + SCAN_BLOCK - 1) / SCAN_BLOCK;   // 293

    // 1. softmax weights
    softmax4_k<<<1, 64, 0, stream>>>(layer_w, w4);

    // 2. degrees + per-node factors
    hipMemsetAsync(deg, 0, (size_t)N_NODES * sizeof(int), stream);
    degree_k<<<(NUM_INTER + 255) / 256, 256, 0, stream>>>(inter_u, inter_i, deg);
    dinv_k<<<(N_NODES + 255) / 256, 256, 0, stream>>>(deg, dinv, d2, rcp, pdeg);

    // 3. exclusive scan pdeg -> row_start (padded CSR)
    block_sum_k<<<nscan_blocks, SCAN_BLOCK, 0, stream>>>(pdeg, bsum, N_NODES);
    scan_bsum_k<<<1, 512, 0, stream>>>(bsum, nscan_blocks);
    scan_block_k<<<nscan_blocks, SCAN_BLOCK, 0, stream>>>(pdeg, bsum, row_start, N_NODES);

    // 4. CSR fill — memset warms L2 so random 4B scatters merge in-cache (R2/R3 evidence)
    hipMemsetAsync(csr_nbr, 0, (size_t)MAX_SLOTS * sizeof(int), stream);
    hipMemsetAsync(fill, 0, (size_t)N_NODES * sizeof(int), stream);
    fill_csr_k<<<(NUM_INTER / 4 + 255) / 256, 256, 0, stream>>>(
        inter_u, inter_i, row_start, fill, csr_nbr);
    pad_fill_k<<<(N_NODES + 255) / 256, 256, 0, stream>>>(deg, row_start, csr_nbr);
    zero_dummy_k<<<1, 64, 0, stream>>>(zA, zB);

    // 5. zA = z0 = dinv ⊙ concat(user_emb, item_emb)
    const int per_node_threads = N_NODES * 16;
    const int per_node_blocks = (per_node_threads + 255) / 256;
    scale_k<<<per_node_blocks, 256, 0, stream>>>(user_emb, item_emb, dinv, zA);

    // 6. two full propagation layers: zB = z1 = P(z0); zA = z2 = P(z1)
    //    (zA's dummy row stays zero — prop writes only real nodes)
    prop_k<<<per_node_blocks, 256, 0, stream>>>(row_start, csr_nbr, d2, zA, zB);
    prop_k<<<per_node_blocks, 256, 0, stream>>>(row_start, csr_nbr, d2, zB, zA);

    // 7. fused: layer-3 pull at queried nodes + layer 0-2 terms + dot product
    fused_score_k<<<(BATCH * 32 + 255) / 256, 256, 0, stream>>>(
        row_start, csr_nbr, dinv, rcp, user_emb, item_emb,
        zB /*z1*/, zA /*z2*/, user_ids, item_ids, w4, out);
}